// Round 3
// baseline (792.373 us; speedup 1.0000x reference)
//
#include <hip/hip_runtime.h>

#define FIN 96
#define HID 64
#define NCLS 5

// ---------------- threefry2x32 (JAX-compatible) ----------------
__device__ __forceinline__ unsigned rotl32(unsigned x, int d) {
    return (x << d) | (x >> (32 - d));
}

__device__ __forceinline__ void threefry2x32(unsigned k0, unsigned k1,
                                             unsigned c0, unsigned c1,
                                             unsigned& o0, unsigned& o1) {
    unsigned ks2 = k0 ^ k1 ^ 0x1BD11BDAu;
    unsigned x0 = c0 + k0, x1 = c1 + k1;
#define RND(r) { x0 += x1; x1 = rotl32(x1, r); x1 ^= x0; }
#define G0 RND(13) RND(15) RND(26) RND(6)
#define G1 RND(17) RND(29) RND(16) RND(24)
    G0; x0 += k1;  x1 += ks2 + 1u;
    G1; x0 += ks2; x1 += k0 + 2u;
    G0; x0 += k0;  x1 += k1 + 3u;
    G1; x0 += k1;  x1 += ks2 + 4u;
    G0; x0 += ks2; x1 += k0 + 5u;
#undef G0
#undef G1
#undef RND
    o0 = x0; o1 = x1;
}

// ---------------- t1 = x @ W1  ([N,96] x [96,64]) ----------------
__global__ __launch_bounds__(256) void gemm1_kernel(
        const float* __restrict__ x, const float* __restrict__ W,
        float* __restrict__ t1, int N) {
    __shared__ float sW[FIN * HID];   // 24 KB
    __shared__ float sX[16 * FIN];    // 6 KB
    for (int i = threadIdx.x; i < FIN * HID; i += 256) sW[i] = W[i];
    int row0 = blockIdx.x * 16;
    long long xbase = (long long)row0 * FIN;
    for (int i = threadIdx.x; i < 16 * FIN; i += 256) {
        long long gi = xbase + i;
        sX[i] = (gi < (long long)N * FIN) ? x[gi] : 0.0f;
    }
    __syncthreads();
    int col = threadIdx.x & 63;
    int rg  = threadIdx.x >> 6;  // 0..3, rows rg*4 .. rg*4+3
    float a0 = 0.f, a1 = 0.f, a2 = 0.f, a3 = 0.f;
    const float* sx = &sX[rg * 4 * FIN];
    for (int k = 0; k < FIN; ++k) {
        float w = sW[k * HID + col];
        a0 += sx[0 * FIN + k] * w;
        a1 += sx[1 * FIN + k] * w;
        a2 += sx[2 * FIN + k] * w;
        a3 += sx[3 * FIN + k] * w;
    }
    int r = row0 + rg * 4;
    if (r + 3 < N) {
        long long base = (long long)r * HID + col;
        t1[base]       = a0;
        t1[base + 64]  = a1;
        t1[base + 128] = a2;
        t1[base + 192] = a3;
    } else {
        float acc[4] = {a0, a1, a2, a3};
        for (int j = 0; j < 4; ++j)
            if (r + j < N) t1[(long long)(r + j) * HID + col] = acc[j];
    }
}

// ---------------- agg1[dst] += t1[src]  (64 floats/edge) ----------------
__global__ __launch_bounds__(256) void scatter1_kernel(
        const int* __restrict__ src, const int* __restrict__ dst,
        const float* __restrict__ t1, float* __restrict__ agg, int E) {
    int tid = blockIdx.x * 256 + threadIdx.x;
    int e = tid >> 4;            // 16 threads per edge
    if (e >= E) return;
    int g = (tid & 15) * 4;      // feature group of 4
    int s = src[e];
    int d = dst[e];
    const float4 v = *reinterpret_cast<const float4*>(&t1[s * HID + g]);
    float* p = &agg[d * HID + g];
    atomicAdd(p + 0, v.x);
    atomicAdd(p + 1, v.y);
    atomicAdd(p + 2, v.z);
    atomicAdd(p + 3, v.w);
}

// ---------------- h = dropout(relu(agg + b1)) ----------------
// JAX partitionable threefry: bits[t] = o0 ^ o1 of threefry2x32(key, (0, t)).
__global__ __launch_bounds__(256) void relu_drop_kernel(
        const float* __restrict__ agg, const float* __restrict__ b1,
        float* __restrict__ h, int total) {
    int t = blockIdx.x * 256 + threadIdx.x;
    if (t >= total) return;
    unsigned o0, o1;
    threefry2x32(0u, 1u, 0u, (unsigned)t, o0, o1);
    unsigned bits = o0 ^ o1;
    float u = __uint_as_float((bits >> 9) | 0x3f800000u) - 1.0f;
    float v = agg[t] + b1[t & 63];
    v = fmaxf(v, 0.0f);
    h[t] = (u < 0.4f) ? (v / 0.4f) : 0.0f;
}

// ---------------- t2 = h @ W2  ([N,64] x [64,5]) ----------------
__global__ __launch_bounds__(256) void gemm2_kernel(
        const float* __restrict__ h, const float* __restrict__ W2,
        float* __restrict__ t2, int N) {
    int idx = blockIdx.x * 256 + threadIdx.x;
    if (idx >= N * NCLS) return;
    int row = idx / NCLS;
    int col = idx - row * NCLS;
    float acc = 0.f;
    const float* hr = &h[row * HID];
    for (int k = 0; k < HID; ++k)
        acc += hr[k] * W2[k * NCLS + col];
    t2[idx] = acc;
}

// ---------------- out = broadcast(b2) ----------------
__global__ __launch_bounds__(256) void bias_out_kernel(
        const float* __restrict__ b2, float* __restrict__ out, int total) {
    int i = blockIdx.x * 256 + threadIdx.x;
    if (i < total) out[i] = b2[i % NCLS];
}

// ---------------- out[dst] += t2[src]  (5 floats/edge) ----------------
__global__ __launch_bounds__(256) void scatter2_kernel(
        const int* __restrict__ src, const int* __restrict__ dst,
        const float* __restrict__ t2, float* __restrict__ out, int E) {
    int tid = blockIdx.x * 256 + threadIdx.x;
    int e = tid >> 3;            // 8 threads per edge, 5 active
    int c = tid & 7;
    if (e >= E || c >= NCLS) return;
    int s = src[e];
    int d = dst[e];
    atomicAdd(&out[d * NCLS + c], t2[s * NCLS + c]);
}

extern "C" void kernel_launch(void* const* d_in, const int* in_sizes, int n_in,
                              void* d_out, int out_size, void* d_ws, size_t ws_size,
                              hipStream_t stream) {
    const float* x   = (const float*)d_in[0];
    const int*   ei  = (const int*)d_in[1];    // int32 per harness contract
    const float* W1  = (const float*)d_in[2];
    const float* b1  = (const float*)d_in[3];
    const float* W2  = (const float*)d_in[4];
    const float* b2  = (const float*)d_in[5];
    float*       out = (float*)d_out;

    const int N = in_sizes[0] / FIN;   // 50000
    const int E = in_sizes[1] / 2;     // 800000
    const int* src = ei;               // edge_index[0]
    const int* dst = ei + E;           // edge_index[1]

    // workspace layout (h reuses t1; t1 is fully consumed by scatter1 first)
    float* t1   = (float*)d_ws;                  // N*64
    float* agg1 = t1 + (size_t)N * HID;          // N*64
    float* h    = t1;                            // reuse
    float* t2   = agg1 + (size_t)N * HID;        // N*5

    hipMemsetAsync(agg1, 0, (size_t)N * HID * sizeof(float), stream);

    gemm1_kernel<<<(N + 15) / 16, 256, 0, stream>>>(x, W1, t1, N);

    int threads1 = E * 16;
    scatter1_kernel<<<(threads1 + 255) / 256, 256, 0, stream>>>(src, dst, t1, agg1, E);

    int total = N * HID;
    relu_drop_kernel<<<(total + 255) / 256, 256, 0, stream>>>(agg1, b1, h, total);

    gemm2_kernel<<<(N * NCLS + 255) / 256, 256, 0, stream>>>(h, W2, t2, N);

    bias_out_kernel<<<(N * NCLS + 255) / 256, 256, 0, stream>>>(b2, out, N * NCLS);

    int threads2 = E * 8;
    scatter2_kernel<<<(threads2 + 255) / 256, 256, 0, stream>>>(src, dst, t2, out, E);
}

// Round 4
// 204.934 us; speedup vs baseline: 3.8665x; 3.8665x over previous
//
#include <hip/hip_runtime.h>

#define FIN 96
#define HID 64
#define NCLS 5

// ---------------- threefry2x32 (JAX-compatible, partitionable path) ----------
__device__ __forceinline__ unsigned rotl32(unsigned x, int d) {
    return (x << d) | (x >> (32 - d));
}

__device__ __forceinline__ void threefry2x32(unsigned k0, unsigned k1,
                                             unsigned c0, unsigned c1,
                                             unsigned& o0, unsigned& o1) {
    unsigned ks2 = k0 ^ k1 ^ 0x1BD11BDAu;
    unsigned x0 = c0 + k0, x1 = c1 + k1;
#define RND(r) { x0 += x1; x1 = rotl32(x1, r); x1 ^= x0; }
#define G0 RND(13) RND(15) RND(26) RND(6)
#define G1 RND(17) RND(29) RND(16) RND(24)
    G0; x0 += k1;  x1 += ks2 + 1u;
    G1; x0 += ks2; x1 += k0 + 2u;
    G0; x0 += k0;  x1 += k1 + 3u;
    G1; x0 += k1;  x1 += ks2 + 4u;
    G0; x0 += ks2; x1 += k0 + 5u;
#undef G0
#undef G1
#undef RND
    o0 = x0; o1 = x1;
}

__device__ __forceinline__ float drop_mask_mul(unsigned t) {
    // JAX partitionable threefry: bits = o0 ^ o1 of threefry(key=(0,1), (0, t))
    unsigned o0, o1;
    threefry2x32(0u, 1u, 0u, t, o0, o1);
    unsigned bits = o0 ^ o1;
    float u = __uint_as_float((bits >> 9) | 0x3f800000u) - 1.0f;
    return (u < 0.4f) ? 2.5f : 0.0f;   // 1/(1-0.6) = 2.5
}

// ---------------- t1 = x @ W1  ([N,96] x [96,64]) ----------------
__global__ __launch_bounds__(256) void gemm1_kernel(
        const float* __restrict__ x, const float* __restrict__ W,
        float* __restrict__ t1, int N) {
    __shared__ float sW[FIN * HID];   // 24 KB
    __shared__ float sX[16 * FIN];    // 6 KB
    for (int i = threadIdx.x; i < FIN * HID; i += 256) sW[i] = W[i];
    int row0 = blockIdx.x * 16;
    long long xbase = (long long)row0 * FIN;
    for (int i = threadIdx.x; i < 16 * FIN; i += 256) {
        long long gi = xbase + i;
        sX[i] = (gi < (long long)N * FIN) ? x[gi] : 0.0f;
    }
    __syncthreads();
    int col = threadIdx.x & 63;
    int rg  = threadIdx.x >> 6;  // rows rg*4 .. rg*4+3
    float a0 = 0.f, a1 = 0.f, a2 = 0.f, a3 = 0.f;
    const float* sx = &sX[rg * 4 * FIN];
    for (int k = 0; k < FIN; ++k) {
        float w = sW[k * HID + col];
        a0 += sx[0 * FIN + k] * w;
        a1 += sx[1 * FIN + k] * w;
        a2 += sx[2 * FIN + k] * w;
        a3 += sx[3 * FIN + k] * w;
    }
    int r = row0 + rg * 4;
    if (r + 3 < N) {
        long long base = (long long)r * HID + col;
        t1[base]       = a0;
        t1[base + 64]  = a1;
        t1[base + 128] = a2;
        t1[base + 192] = a3;
    } else {
        float acc[4] = {a0, a1, a2, a3};
        for (int j = 0; j < 4; ++j)
            if (r + j < N) t1[(long long)(r + j) * HID + col] = acc[j];
    }
}

// ---------------- CSR build ----------------
__global__ __launch_bounds__(256) void hist_kernel(
        const int* __restrict__ dst, int* __restrict__ count, int E) {
    int e = blockIdx.x * 256 + threadIdx.x;
    if (e < E) atomicAdd(&count[dst[e]], 1);
}

// per-tile sums (tiles of 256)
__global__ __launch_bounds__(256) void scanA_kernel(
        const int* __restrict__ count, int* __restrict__ tileSum, int N) {
    __shared__ int s[256];
    int i = blockIdx.x * 256 + threadIdx.x;
    s[threadIdx.x] = (i < N) ? count[i] : 0;
    __syncthreads();
    for (int off = 128; off > 0; off >>= 1) {
        if (threadIdx.x < off) s[threadIdx.x] += s[threadIdx.x + off];
        __syncthreads();
    }
    if (threadIdx.x == 0) tileSum[blockIdx.x] = s[0];
}

// exclusive scan of tile sums (single block, serial carry over chunks of 256)
__global__ __launch_bounds__(256) void scanB_kernel(
        const int* __restrict__ tileSum, int* __restrict__ tileOff, int T) {
    __shared__ int s[256];
    __shared__ int carry;
    if (threadIdx.x == 0) carry = 0;
    __syncthreads();
    for (int base = 0; base < T; base += 256) {
        int i = base + threadIdx.x;
        int v = (i < T) ? tileSum[i] : 0;
        s[threadIdx.x] = v;
        __syncthreads();
        for (int off = 1; off < 256; off <<= 1) {
            int x = (threadIdx.x >= off) ? s[threadIdx.x - off] : 0;
            __syncthreads();
            s[threadIdx.x] += x;
            __syncthreads();
        }
        if (i < T) tileOff[i] = s[threadIdx.x] - v + carry;
        __syncthreads();
        if (threadIdx.x == 255) carry += s[255];
        __syncthreads();
    }
}

// per-element exclusive offsets; cursor = copy of offset
__global__ __launch_bounds__(256) void scanC_kernel(
        const int* __restrict__ count, const int* __restrict__ tileOff,
        int* __restrict__ offset, int* __restrict__ cursor, int N) {
    __shared__ int s[256];
    int i = blockIdx.x * 256 + threadIdx.x;
    int v = (i < N) ? count[i] : 0;
    s[threadIdx.x] = v;
    __syncthreads();
    for (int off = 1; off < 256; off <<= 1) {
        int x = (threadIdx.x >= off) ? s[threadIdx.x - off] : 0;
        __syncthreads();
        s[threadIdx.x] += x;
        __syncthreads();
    }
    if (i < N) {
        int excl = s[threadIdx.x] - v + tileOff[blockIdx.x];
        offset[i] = excl;
        cursor[i] = excl;
    }
}

__global__ __launch_bounds__(256) void fill_kernel(
        const int* __restrict__ src, const int* __restrict__ dst,
        int* __restrict__ cursor, int* __restrict__ sortedSrc, int E) {
    int e = blockIdx.x * 256 + threadIdx.x;
    if (e >= E) return;
    int slot = atomicAdd(&cursor[dst[e]], 1);
    sortedSrc[slot] = src[e];
}

// ---------------- layer-1 aggregate + bias + relu + dropout (fused) --------
// One wave per dst node; lane = feature column.
__global__ __launch_bounds__(256) void agg1_fused_kernel(
        const int* __restrict__ offset, const int* __restrict__ count,
        const int* __restrict__ sortedSrc, const float* __restrict__ t1,
        const float* __restrict__ b1, float* __restrict__ h, int N) {
    int node = blockIdx.x * 4 + (threadIdx.x >> 6);
    int lane = threadIdx.x & 63;
    if (node >= N) return;
    int beg = offset[node];
    int end = beg + count[node];
    float acc = 0.0f;
    int i = beg;
    for (; i + 1 < end; i += 2) {
        int s0 = sortedSrc[i];
        int s1 = sortedSrc[i + 1];
        acc += t1[s0 * HID + lane] + t1[s1 * HID + lane];
    }
    if (i < end) acc += t1[sortedSrc[i] * HID + lane];
    float v = fmaxf(acc + b1[lane], 0.0f);
    unsigned t = (unsigned)(node * HID + lane);
    h[t] = v * drop_mask_mul(t);
}

// ---------------- t2 = h @ W2  ([N,64] x [64,5]) ----------------
__global__ __launch_bounds__(256) void gemm2_kernel(
        const float* __restrict__ h, const float* __restrict__ W2,
        float* __restrict__ t2, int N) {
    int idx = blockIdx.x * 256 + threadIdx.x;
    if (idx >= N * NCLS) return;
    int row = idx / NCLS;
    int col = idx - row * NCLS;
    float acc = 0.f;
    const float* hr = &h[row * HID];
    for (int k = 0; k < HID; ++k)
        acc += hr[k] * W2[k * NCLS + col];
    t2[idx] = acc;
}

// ---------------- layer-2 aggregate + bias (fused, gather) ----------------
// 8 threads per node (5 active), c = class.
__global__ __launch_bounds__(256) void out_fused_kernel(
        const int* __restrict__ offset, const int* __restrict__ count,
        const int* __restrict__ sortedSrc, const float* __restrict__ t2,
        const float* __restrict__ b2, float* __restrict__ out, int N) {
    int tid = blockIdx.x * 256 + threadIdx.x;
    int node = tid >> 3;
    int c = tid & 7;
    if (node >= N || c >= NCLS) return;
    int beg = offset[node];
    int end = beg + count[node];
    float acc = b2[c];
    for (int i = beg; i < end; ++i) {
        int s = sortedSrc[i];
        acc += t2[s * NCLS + c];
    }
    out[node * NCLS + c] = acc;
}

// ================= fallback (atomic path, known-good from round 3) =========
__global__ __launch_bounds__(256) void scatter1_kernel(
        const int* __restrict__ src, const int* __restrict__ dst,
        const float* __restrict__ t1, float* __restrict__ agg, int E) {
    int tid = blockIdx.x * 256 + threadIdx.x;
    int e = tid >> 4;
    if (e >= E) return;
    int g = (tid & 15) * 4;
    int s = src[e];
    int d = dst[e];
    const float4 v = *reinterpret_cast<const float4*>(&t1[s * HID + g]);
    float* p = &agg[d * HID + g];
    atomicAdd(p + 0, v.x);
    atomicAdd(p + 1, v.y);
    atomicAdd(p + 2, v.z);
    atomicAdd(p + 3, v.w);
}

__global__ __launch_bounds__(256) void relu_drop_kernel(
        const float* __restrict__ agg, const float* __restrict__ b1,
        float* __restrict__ h, int total) {
    int t = blockIdx.x * 256 + threadIdx.x;
    if (t >= total) return;
    float v = fmaxf(agg[t] + b1[t & 63], 0.0f);
    h[t] = v * drop_mask_mul((unsigned)t);
}

__global__ __launch_bounds__(256) void bias_out_kernel(
        const float* __restrict__ b2, float* __restrict__ out, int total) {
    int i = blockIdx.x * 256 + threadIdx.x;
    if (i < total) out[i] = b2[i % NCLS];
}

__global__ __launch_bounds__(256) void scatter2_kernel(
        const int* __restrict__ src, const int* __restrict__ dst,
        const float* __restrict__ t2, float* __restrict__ out, int E) {
    int tid = blockIdx.x * 256 + threadIdx.x;
    int e = tid >> 3;
    int c = tid & 7;
    if (e >= E || c >= NCLS) return;
    int s = src[e];
    int d = dst[e];
    atomicAdd(&out[d * NCLS + c], t2[s * NCLS + c]);
}

// ===========================================================================
extern "C" void kernel_launch(void* const* d_in, const int* in_sizes, int n_in,
                              void* d_out, int out_size, void* d_ws, size_t ws_size,
                              hipStream_t stream) {
    const float* x   = (const float*)d_in[0];
    const int*   ei  = (const int*)d_in[1];    // int32
    const float* W1  = (const float*)d_in[2];
    const float* b1  = (const float*)d_in[3];
    const float* W2  = (const float*)d_in[4];
    const float* b2  = (const float*)d_in[5];
    float*       out = (float*)d_out;

    const int N = in_sizes[0] / FIN;   // 50000
    const int E = in_sizes[1] / 2;     // 800000
    const int* src = ei;               // edge_index[0]
    const int* dst = ei + E;           // edge_index[1]

    const int T = (N + 255) / 256;     // scan tiles

    // workspace layout (CSR path)
    float* t1        = (float*)d_ws;                    // N*HID
    float* h         = t1 + (size_t)N * HID;            // N*HID
    float* t2        = h + (size_t)N * HID;             // N*NCLS
    int*   count     = (int*)(t2 + (size_t)N * NCLS);   // N
    int*   offset    = count + N;                       // N
    int*   cursor    = offset + N;                      // N
    int*   tileSum   = cursor + N;                      // T (<=512 padded)
    int*   tileOff   = tileSum + 512;                   // T
    int*   sortedSrc = tileOff + 512;                   // E
    size_t needed = (size_t)(sortedSrc + E - (int*)d_ws) * sizeof(int);

    if (ws_size >= needed) {
        // ---------- CSR gather path (no f32 atomics) ----------
        hipMemsetAsync(count, 0, (size_t)N * sizeof(int), stream);

        gemm1_kernel<<<(N + 15) / 16, 256, 0, stream>>>(x, W1, t1, N);

        hist_kernel<<<(E + 255) / 256, 256, 0, stream>>>(dst, count, E);
        scanA_kernel<<<T, 256, 0, stream>>>(count, tileSum, N);
        scanB_kernel<<<1, 256, 0, stream>>>(tileSum, tileOff, T);
        scanC_kernel<<<T, 256, 0, stream>>>(count, tileOff, offset, cursor, N);
        fill_kernel<<<(E + 255) / 256, 256, 0, stream>>>(src, dst, cursor, sortedSrc, E);

        agg1_fused_kernel<<<(N + 3) / 4, 256, 0, stream>>>(
            offset, count, sortedSrc, t1, b1, h, N);

        gemm2_kernel<<<(N * NCLS + 255) / 256, 256, 0, stream>>>(h, W2, t2, N);

        out_fused_kernel<<<(N * 8 + 255) / 256, 256, 0, stream>>>(
            offset, count, sortedSrc, t2, b2, out, N);
    } else {
        // ---------- fallback: round-3 atomic path ----------
        float* agg1 = h;   // reuse slot
        hipMemsetAsync(agg1, 0, (size_t)N * HID * sizeof(float), stream);
        gemm1_kernel<<<(N + 15) / 16, 256, 0, stream>>>(x, W1, t1, N);
        scatter1_kernel<<<(E * 16 + 255) / 256, 256, 0, stream>>>(src, dst, t1, agg1, E);
        int total = N * HID;
        relu_drop_kernel<<<(total + 255) / 256, 256, 0, stream>>>(agg1, b1, t1, total);
        gemm2_kernel<<<(N * NCLS + 255) / 256, 256, 0, stream>>>(t1, W2, t2, N);
        bias_out_kernel<<<(N * NCLS + 255) / 256, 256, 0, stream>>>(b2, out, N * NCLS);
        scatter2_kernel<<<(E * 8 + 255) / 256, 256, 0, stream>>>(src, dst, t2, out, E);
    }
}